// Round 12
// baseline (169.432 us; speedup 1.0000x reference)
//
#include <hip/hip_runtime.h>

#define NBLOCK 64
#define TPB 256
#define GRID 512   // persistent: 2 blocks/CU; block p owns a contiguous 1024-voice range
#define ROWU 36    // u32 stride per voice row: 32 f16-pairs + inv @ [32] + pad (16B-aligned)

typedef __fp16 half2_t __attribute__((ext_vector_type(2)));   // matches cvt_pkrtz return
typedef float  f32x4  __attribute__((ext_vector_type(4)));    // native vec for nt-store builtin
union PK { half2_t h2; unsigned int u; };

// Hardware sine: v_sin_f32 computes sin(2*pi*x); v_fract makes the input
// range always valid. Validated r8-r10 (passed, absmax unchanged).
__device__ __forceinline__ float sin_rev(float xrev) {
    return __builtin_amdgcn_sinf(__builtin_amdgcn_fractf(xrev));
}

// Exact floored fmod vs float32(2*pi), bit-matching numpy fp32 semantics.
__device__ __forceinline__ float mod_two_pi(float x) {
    const float Y = 6.2831853071795864769f;       // rounds to float32 2*pi
    float kf = floorf(__fdiv_rn(x, Y));
    float m = fmaf(-kf, Y, x);
    if (m < 0.0f)  { kf -= 1.0f; m = fmaf(-kf, Y, x); }
    if (m >= Y)    { kf += 1.0f; m = fmaf(-kf, Y, x); }
    return m;
}

// Round-11 retry (r11 was a builtin-type compile fix only):
//   NON-TEMPORAL stores — decouple from the poisoned cache. Each rep the
//   harness fills 570 MB at 6.8 TB/s right before our kernel -> L3 (256 MB)
//   is full of dirty poison when we start. Write-allocating stores evict a
//   dirty victim per 128B line -> ~2x effective write cost + MC contention,
//   matching the measured ~79us where no issue-side model could (r2-r10:
//   granularity/barriers/occupancy/VALU/stream/vmcnt levers all ~0-5us).
//   Output is write-once/never-reread => nt stores: no allocation, no
//   victim coupling, straight write-combine to HBM (the fill's own path).
//   Inputs stay cached (L3-warm across reps: FETCH 11.7 MB < 23 MB).
//   Everything else byte-identical to r10 (best, 163.5).
__global__ __launch_bounds__(TPB, 2)
void fm_synth_kernel(const float* __restrict__ fm_params,
                     const float* __restrict__ f0_hz,
                     const float* __restrict__ phase_state,
                     float* __restrict__ out, int nv)
{
    __shared__ unsigned int lds[4 * 32 * ROWU];   // 4 waves x 32 rows x 36 u32 = 18432 B

    int tid  = threadIdx.x;
    int lane = tid & 63;
    int wv   = tid >> 6;
    f32x4* out4 = (f32x4*)out;
    f32x4* pe4  = (f32x4*)(out + (size_t)nv * NBLOCK);
    const float2* fm2 = (const float2*)fm_params;
    const float4* ps4 = (const float4*)phase_state;
    unsigned int* slab = &lds[wv * (32 * ROWU)];
    int grp = lane >> 5;               // which sub-chunk this lane deposits
    int row = lane & 31;               // row within sub-chunk

    // block p covers a CONTIGUOUS voice range (sequential HBM stream, r9)
    int nch = (nv + (int)gridDim.x * TPB - 1) / ((int)gridDim.x * TPB);
    int vstart = blockIdx.x * nch * TPB;

    // ---- pipeline prologue: issue chunk-0 input loads ---------------------
    int bc0 = min(vstart + tid, nv - 1);
    float2 i01 = fm2[bc0 * 3 + 0];
    float2 i23 = fm2[bc0 * 3 + 1];
    float2 i45 = fm2[bc0 * 3 + 2];
    float  vf0 = f0_hz[bc0];
    float4 ist = ps4[bc0];

#pragma unroll 1
    for (int c = 0; c < nch; ++c) {
        int base = vstart + c * TPB;
        if (base >= nv) break;
        bool live = (base + tid) < nv;

        // ---- PREFETCH chunk c+1 inputs (issued before this chunk's
        //      stores -> oldest in vm queue; consuming them next iter waits
        //      a counted vmcnt, not a store drain — r10, kept) -------------
        int bcn = min(vstart + (c + 1) * TPB + tid, nv - 1);
        float2 n01 = fm2[bcn * 3 + 0];
        float2 n23 = fm2[bcn * 3 + 1];
        float2 n45 = fm2[bcn * 3 + 2];
        float  nf0 = f0_hz[bcn];
        float4 nst = ps4[bcn];

        // ---- params — exact fp32 op order matching the reference ---------
        const float TWO_PI  = 6.2831853071795864769f;
        const float INV2PI  = 0.15915494309189533577f; // float32(1/(2*pi))
        float f0  = fmaxf(vf0, 1.0f);
        float r1  = __fadd_rn(0.25f, __fmul_rn(i01.y, 15.75f));
        float fb1 = __fmul_rn(i23.x, 0.95f);
        float d2  = __fmul_rn(i23.y, 10.0f);
        float r2  = __fadd_rn(0.25f, __fmul_rn(i45.x, 15.75f));
        float fb2 = __fmul_rn(i45.y, 0.95f);
        float inc1 = __fdiv_rn(__fmul_rn(__fmul_rn(TWO_PI, f0), r1), 16000.0f);
        float inc2 = __fdiv_rn(__fmul_rn(__fmul_rn(TWO_PI, f0), r2), 16000.0f);

        float start1 = ist.x, start2 = ist.y;
        float l1 = ist.z, l2 = ist.w;

        // phase_end x/y (exact radian math), frees regs early
        float pex = mod_two_pi(__fadd_rn(start1, __fmul_rn(64.0f, inc1)));
        float pey = mod_two_pi(__fadd_rn(start2, __fmul_rn(64.0f, inc2)));

        // revolution-space copies for the hw-sin loop
        float inc1r   = inc1 * INV2PI;
        float inc2r   = inc2 * INV2PI;
        float start1r = start1 * INV2PI;
        float start2r = start2 * INV2PI;
        float fb1r    = fb1 * INV2PI;
        float fb2r    = fb2 * INV2PI;
        float d2r     = d2  * INV2PI;

        // ---- 64-step recurrence (rev space, hw sin); ss inline; fp16 pack
        unsigned int smph[32];
        float ss = 0.0f;
        float prev = 0.0f;
#pragma unroll
        for (int t = 0; t < NBLOCK; ++t) {
            float tf  = (float)t;
            float ph1 = fmaf(tf, inc1r, start1r);
            float ph2 = fmaf(tf, inc2r, start2r);
            float o1 = sin_rev(fmaf(fb1r, l1, ph1));
            float o2 = sin_rev(fmaf(d2r, o1, fmaf(fb2r, l2, ph2)));
            l1 = o1;
            l2 = o2;
            ss = fmaf(o2, o2, ss);
            if (t & 1) {
                PK pk; pk.h2 = __builtin_amdgcn_cvt_pkrtz(prev, o2);
                smph[t >> 1] = pk.u;
            } else {
                prev = o2;
            }
        }
        float inv = 1.0f / sqrtf(ss * 0.015625f + 1e-5f);

        // ---- store phase (all stores non-temporal) ------------------------
        f32x4 pe;
        pe.x = pex;
        pe.y = pey;
        pe.z = l1;
        pe.w = l2;
        if (live) __builtin_nontemporal_store(pe, &pe4[base + tid]);

        // audio: per-wave slab, 2 sub-chunks x 32 voices, no barriers.
        // Slab WAR vs previous chunk's ds_reads is intra-wave (lgkmcnt).
#pragma unroll
        for (int cc = 0; cc < 2; ++cc) {
            if (grp == cc) {           // 32 lanes deposit whole packed rows
                unsigned int* slot = &slab[row * ROWU];
#pragma unroll
                for (int i = 0; i < 8; ++i) {
                    uint4 w;
                    w.x = smph[4 * i + 0];
                    w.y = smph[4 * i + 1];
                    w.z = smph[4 * i + 2];
                    w.w = smph[4 * i + 3];
                    *(uint4*)&slot[4 * i] = w;
                }
                slot[32] = __float_as_uint(inv);
            }
            // all 64 lanes: transposed read + dense 8 KB contiguous segment
            int vbase = base + wv * 64 + cc * 32;
            size_t gb4 = (size_t)vbase * 16;       // float4 units
#pragma unroll
            for (int j = 0; j < 8; ++j) {
                int f    = j * 64 + lane;          // 0..511 flat float4 idx
                int voff = f >> 4;                 // voice within sub-chunk
                int p    = f & 15;                 // float4 within row
                const unsigned int* rp = &slab[voff * ROWU + 2 * p];
                unsigned int u0 = rp[0];
                unsigned int u1 = rp[1];           // ds_read_b64 (8B-aligned)
                float vinv = __uint_as_float(slab[voff * ROWU + 32]);
                PK a; a.u = u0;
                PK q; q.u = u1;
                f32x4 val;
                val.x = (float)a.h2.x * vinv;
                val.y = (float)a.h2.y * vinv;
                val.z = (float)q.h2.x * vinv;
                val.w = (float)q.h2.y * vinv;
                if (vbase + voff < nv)
                    __builtin_nontemporal_store(val, &out4[gb4 + f]);
            }
        }

        // ---- rotate pipeline registers -----------------------------------
        i01 = n01; i23 = n23; i45 = n45; vf0 = nf0; ist = nst;
    }
}

extern "C" void kernel_launch(void* const* d_in, const int* in_sizes, int n_in,
                              void* d_out, int out_size, void* d_ws, size_t ws_size,
                              hipStream_t stream) {
    const float* fm_params   = (const float*)d_in[0];
    const float* f0_hz       = (const float*)d_in[1];
    const float* phase_state = (const float*)d_in[2];
    float* out = (float*)d_out;
    int nv = in_sizes[1];                      // f0_hz has one element per voice
    int nblocks = (nv + TPB - 1) / TPB;
    int grid = nblocks < GRID ? nblocks : GRID;
    if (grid < 1) grid = 1;
    fm_synth_kernel<<<grid, TPB, 0, stream>>>(fm_params, f0_hz, phase_state, out, nv);
}